// Round 10
// baseline (84.733 us; speedup 1.0000x reference)
//
#include <hip/hip_runtime.h>

typedef unsigned short u16;
typedef unsigned int u32;
typedef __attribute__((ext_vector_type(8))) short short8;
typedef __attribute__((ext_vector_type(4))) float f32x4;

#define LOG_SQRT_2PI 0.9189385332046727f
#define NB 16
#define NL 512
#define NE 512
#define ZWIN 20.0f
#define MAXTB 32

__device__ __forceinline__ u16 f2bf(float x) {
    u32 u = __builtin_bit_cast(u32, x);
    u += 0x7fffu + ((u >> 16) & 1u);
    return (u16)(u >> 16);
}

__device__ __forceinline__ float bf2f(u16 h) {
    return __builtin_bit_cast(float, (u32)h << 16);
}

__device__ __forceinline__ void gload_lds16(const u16* g, u16* l) {
    __builtin_amdgcn_global_load_lds(
        (__attribute__((address_space(1))) void*)(u16*)g,
        (__attribute__((address_space(3))) void*)l,
        16, 0, 0);
}

// ---------------- K1: xc -> XcT[b][e][l] bf16 + per-eblock partial dot(xc, wproj) ----------------
__global__ void k_xc(const float* __restrict__ x, const float* __restrict__ en,
                     const float* __restrict__ pt,
                     const float* __restrict__ wn, const float* __restrict__ bn,
                     const float* __restrict__ wq, const float* __restrict__ bq,
                     const float* __restrict__ wproj,
                     u16* __restrict__ XcT, float* __restrict__ dot8) {
    __shared__ u16 tile[64][66];
    __shared__ float pdl[4][64];
    int b = blockIdx.z;
    int l0 = blockIdx.y * 64, e0 = blockIdx.x * 64;
    int tid = threadIdx.x;         // 256
    int lr = tid >> 6, c = tid & 63;
    int e = e0 + c;
    float wn0 = wn[e * 3], wn1 = wn[e * 3 + 1], wn2 = wn[e * 3 + 2];
    float wq0 = wq[e * 3], wq1 = wq[e * 3 + 1], wq2 = wq[e * 3 + 2];
    float bias = bn[e] + bq[e];
    #pragma unroll 4
    for (int it = 0; it < 16; ++it) {
        int ll = lr * 16 + it;
        int l = l0 + ll;
        int base = b * NL;
        float em1 = (l > 0)   ? en[base + l - 1] : 0.f;
        float ev  = en[base + l];
        float ep1 = (l < 511) ? en[base + l + 1] : 0.f;
        float pm1 = (l > 0)   ? pt[base + l - 1] : 0.f;
        float pv  = pt[base + l];
        float pp1 = (l < 511) ? pt[base + l + 1] : 0.f;
        float v = x[((size_t)(base + l)) * NE + e]
                + wn0 * em1 + wn1 * ev + wn2 * ep1
                + wq0 * pm1 + wq1 * pv + wq2 * pp1 + bias;
        tile[ll][c] = f2bf(v);
    }
    __syncthreads();
    float pd = 0.f;
    #pragma unroll 4
    for (int it = 0; it < 16; ++it) {
        int eo = lr + 4 * it;  // 0..63
        u16 h = tile[c][eo];
        XcT[((size_t)b * NE + (e0 + eo)) * NL + l0 + c] = h;
        pd = fmaf(bf2f(h), wproj[e0 + eo], pd);
    }
    pdl[lr][c] = pd;
    __syncthreads();
    if (lr == 0) {
        float s = (pdl[0][c] + pdl[1][c]) + (pdl[2][c] + pdl[3][c]);
        dot8[((size_t)(b * NL + l0 + c)) * 8 + blockIdx.x] = s;
    }
}

// ---------------- K2: taps(local) + cumsum means + ranges/inv_std/A + window table ----------------
__global__ void k_pre(const int* __restrict__ dint, const float* __restrict__ df,
                      const int* __restrict__ lens,
                      const float* __restrict__ wproj, const float* __restrict__ wd,
                      const float* __restrict__ bd, const float* __restrict__ bproj,
                      const float* __restrict__ dot8,
                      float* __restrict__ means, float* __restrict__ inv_std,
                      float* __restrict__ Aarr, int2* __restrict__ win, int ntb) {
    int b = blockIdx.x, l = threadIdx.x;  // 512 threads
    __shared__ float s[NL];
    __shared__ float red[4][8];
    __shared__ float tarr[4];
    __shared__ int slo[MAXTB], shi[MAXTB];
    {
        float wp = wproj[l];
        float v[4] = {wp * wd[l * 3 + 0], wp * wd[l * 3 + 1], wp * wd[l * 3 + 2], wp * bd[l]};
        int lane = l & 63, wv = l >> 6;
        #pragma unroll
        for (int i = 0; i < 4; i++) {
            float t = v[i];
            for (int m = 32; m; m >>= 1) t += __shfl_xor(t, m);
            if (lane == 0) red[i][wv] = t;
        }
    }
    if (l < ntb) { slo[l] = NL; shi[l] = -1; }
    float d = (float)dint[b * NL + l];
    s[l] = d;
    __syncthreads();
    if (l < 4) {
        float t = 0.f;
        for (int w2 = 0; w2 < 8; w2++) t += red[l][w2];
        if (l == 3) t += bproj[0];
        tarr[l] = t;
    }
    for (int off = 1; off < NL; off <<= 1) {
        float v = (l >= off) ? s[l - off] : 0.0f;
        __syncthreads();
        s[l] += v;
        __syncthreads();
    }
    float mean = s[l] - 0.5f * d;
    means[b * NL + l] = mean;
    int base = b * NL;
    float dot;
    {
        const float4* dp = (const float4*)(dot8 + ((size_t)(base + l)) * 8);
        float4 a = dp[0], bb4 = dp[1];
        dot = ((a.x + a.y) + (a.z + a.w)) + ((bb4.x + bb4.y) + (bb4.z + bb4.w));
    }
    float dm1 = (l > 0)   ? df[base + l - 1] : 0.f;
    float d0  = df[base + l];
    float dp1 = (l < 511) ? df[base + l + 1] : 0.f;
    float lin = dot + tarr[3]
              + tarr[0] * dm1 + tarr[1] * d0 + tarr[2] * dp1;
    float r = (lin > 20.f) ? lin : log1pf(expf(lin));
    bool pad = (l >= lens[b]);
    if (pad) r = 1.0f;
    float sd = fmaxf(r, 0.001f);
    inv_std[base + l] = 1.0f / sd;
    Aarr[base + l] = pad ? -1e30f : (-logf(sd) - LOG_SQRT_2PI);
    if (!pad) {
        float fl = mean - ZWIN * sd - 1.0f;
        float fh = mean + ZWIN * sd + 1.0f;
        for (int tb = 0; tb < ntb; ++tb) {
            float t_lo = tb * 128.0f + 0.5f, t_hi = tb * 128.0f + 127.5f;
            if (fl <= t_hi && fh >= t_lo) {
                atomicMin(&slo[tb], l);
                atomicMax(&shi[tb], l);
            }
        }
    }
    __syncthreads();
    if (l < ntb) win[b * MAXTB + l] = make_int2(slo[l], shi[l]);
}

// ---------------- K3: banded GEMM; rn in-block; out_w rows split across e-blocks ----------------
__global__ __launch_bounds__(256) void k_gemm(const u16* __restrict__ XcT,
                                              const float* __restrict__ frames,
                                              const float* __restrict__ means,
                                              const float* __restrict__ inv_std,
                                              const float* __restrict__ Aarr,
                                              const int2* __restrict__ win,
                                              float* __restrict__ out,
                                              float* __restrict__ wout, int T) {
    __shared__ float4 sq[NL];
    __shared__ float fts[128];
    __shared__ float part[2][128];
    __shared__ float rvs[128];
    __shared__ u16 At[2][128][32];
    __shared__ u16 Bt[2][128][32];
    int b = blockIdx.z;
    int t0 = blockIdx.y * 128;
    int e0 = blockIdx.x * 128;
    int tid = threadIdx.x;
    int lane = tid & 63, wid = tid >> 6;
    int wm = wid >> 1, wn = wid & 1;
    const u16* Bb = XcT + (size_t)b * NE * NL;

    int2 w = win[b * MAXTB + blockIdx.y];
    int ks0 = 0, nst = 0;
    if (w.x <= w.y) { ks0 = w.x >> 5; nst = (w.y >> 5) - ks0 + 1; }
    int bl0 = ks0 * 32, bl1 = (ks0 + nst) * 32;

    // band-restricted stats load
    for (int i = bl0 + tid; i < bl1; i += 256)
        sq[i] = make_float4(means[b * NL + i], inv_std[b * NL + i], Aarr[b * NL + i], 0.f);
    if (tid < 128) fts[tid] = (t0 + tid < T) ? frames[t0 + tid] : -1e9f;

    __syncthreads();  // sq, fts ready

    // --- per-t normalizer: 2 threads per t sum the band ---
    if (nst > 0) {
        int tr = tid & 127, h = tid >> 7;
        float ftr = fts[tr];
        float ssum = 0.f;
        for (int l = w.x + h; l <= w.y; l += 2) {
            float4 q = sq[l];
            float z = (ftr - q.x) * q.y;
            ssum += __expf(fmaf(z, -0.5f * z, q.z));
        }
        part[h][tr] = ssum;
    }
    __syncthreads();
    if (tid < 128) rvs[tid] = 1.0f / (part[0][tid] + part[1][tid] + 1e-20f);
    __syncthreads();

    int ta = tid >> 1;        // A-row (t offset) this thread fills
    int ha = (tid & 1) * 16;  // which 16-col half
    float ft = fts[ta];
    float rv = rvs[ta];

    int srow = wid * 32 + (lane >> 2);
    int skc = (lane & 3) * 8;

    f32x4 acc[4][4];
    #pragma unroll
    for (int m = 0; m < 4; m++)
        #pragma unroll
        for (int n = 0; n < 4; n++)
            #pragma unroll
            for (int k = 0; k < 4; k++) acc[m][n][k] = 0.0f;

    auto stage = [&](int buf, int ks) {
        int l0 = ks * 32;
        const u16* gb = Bb + (size_t)(e0 + srow) * NL + l0 + skc;
        gload_lds16(gb, &Bt[buf][wid * 32][0]);
        gload_lds16(gb + 16 * NL, &Bt[buf][wid * 32 + 16][0]);
        u32 pk[8];
        #pragma unroll
        for (int jj = 0; jj < 8; ++jj) {
            float4 q0 = sq[l0 + ha + jj * 2];
            float4 q1 = sq[l0 + ha + jj * 2 + 1];
            float z0 = (ft - q0.x) * q0.y;
            float p0 = __expf(fmaf(z0, -0.5f * z0, q0.z)) * rv;
            float z1 = (ft - q1.x) * q1.y;
            float p1 = __expf(fmaf(z1, -0.5f * z1, q1.z)) * rv;
            pk[jj] = (u32)f2bf(p0) | ((u32)f2bf(p1) << 16);
        }
        *(uint4*)&At[buf][ta][ha]     = make_uint4(pk[0], pk[1], pk[2], pk[3]);
        *(uint4*)&At[buf][ta][ha + 8] = make_uint4(pk[4], pk[5], pk[6], pk[7]);
    };

    int fr = lane & 15, fk = (lane >> 4) * 8;
    if (nst > 0) {
        stage(0, ks0);
        for (int s = 0; s < nst; ++s) {
            __syncthreads();  // buf[s&1] (ds_writes + gload_lds) visible
            if (s + 1 < nst) stage((s + 1) & 1, ks0 + s + 1);
            int buf = s & 1;
            short8 a[4], bb[4];
            #pragma unroll
            for (int m = 0; m < 4; m++)
                a[m] = *(const short8*)&At[buf][wm * 64 + m * 16 + fr][fk];
            #pragma unroll
            for (int n = 0; n < 4; n++)
                bb[n] = *(const short8*)&Bt[buf][wn * 64 + n * 16 + fr][fk];
            #pragma unroll
            for (int m = 0; m < 4; m++)
                #pragma unroll
                for (int n = 0; n < 4; n++)
                    acc[m][n] = __builtin_amdgcn_mfma_f32_16x16x32_bf16(a[m], bb[n], acc[m][n], 0, 0, 0);
        }
    }

    // --- C-write (non-temporal: out is write-once) ---
    int r4 = (lane >> 4) * 4;
    #pragma unroll
    for (int m = 0; m < 4; m++) {
        int tb2 = t0 + wm * 64 + m * 16 + r4;
        #pragma unroll
        for (int j = 0; j < 4; j++) {
            int t = tb2 + j;
            if (t < T) {
                float* orow = out + ((size_t)b * T + t) * NE + e0 + wn * 64 + (lane & 15);
                #pragma unroll
                for (int n = 0; n < 4; n++)
                    __builtin_nontemporal_store(acc[m][n][j], &orow[n * 16]);
            }
        }
    }

    // --- out_w epilogue: this e-block writes rows [e0, e0+128), lane <-> t coalesced ---
    if (t0 < T) {
        int tcnt = T - t0; if (tcnt > 128) tcnt = 128;
        int rbeg = e0, rend = e0 + 128;
        int ib0 = bl0 > rbeg ? bl0 : rbeg;
        int ib1 = bl1 < rend ? bl1 : rend;
        int t4 = (tid & 31) * 4, rsub = tid >> 5;     // 8 rows per pass
        bool t4full = (t4 + 4 <= tcnt);
        f32x4 z4 = {0.f, 0.f, 0.f, 0.f};
        auto zfill = [&](int r0, int r1) {
            for (int l = r0 + rsub; l < r1; l += 8) {
                float* d = wout + ((size_t)b * NL + l) * T + t0 + t4;
                if (t4full) __builtin_nontemporal_store(z4, (f32x4*)d);
                else { for (int u = 0; u < 4 && t4 + u < tcnt; ++u) d[u] = 0.f; }
            }
        };
        if (ib0 >= ib1) {
            zfill(rbeg, rend);
        } else {
            zfill(rbeg, ib0);
            zfill(ib1, rend);
            int tt = tid & 127, half = tid >> 7;
            if (tt < tcnt) {
                float ftl = fts[tt], rvl = rvs[tt];
                float* dstc = wout + (size_t)b * NL * T + t0 + tt;
                for (int l = ib0 + half; l < ib1; l += 2) {
                    float4 q = sq[l];
                    float z = (ftl - q.x) * q.y;
                    float val = __expf(fmaf(z, -0.5f * z, q.z)) * rvl;
                    __builtin_nontemporal_store(val, &dstc[(size_t)l * T]);
                }
            }
        }
    }
}

extern "C" void kernel_launch(void* const* d_in, const int* in_sizes, int n_in,
                              void* d_out, int out_size, void* d_ws, size_t ws_size,
                              hipStream_t stream) {
    const float* x      = (const float*)d_in[0];
    const float* df     = (const float*)d_in[1];
    const int*   dint   = (const int*)d_in[2];
    const float* en     = (const float*)d_in[3];
    const float* pt     = (const float*)d_in[4];
    const int*   lens   = (const int*)d_in[5];
    const float* frames = (const float*)d_in[6];
    const float* wd     = (const float*)d_in[7];
    const float* bd     = (const float*)d_in[8];
    const float* wn     = (const float*)d_in[9];
    const float* bn     = (const float*)d_in[10];
    const float* wq     = (const float*)d_in[11];
    const float* bq     = (const float*)d_in[12];
    const float* wproj  = (const float*)d_in[13];
    const float* bproj  = (const float*)d_in[14];

    int T = in_sizes[6];
    int ntb = (T + 127) / 128;   // <= 32

    char* ws = (char*)d_ws;
    float* means   = (float*)(ws);             // B*L
    float* inv_std = (float*)(ws + 32768);     // B*L
    float* Aarr    = (float*)(ws + 65536);     // B*L
    float* dot8    = (float*)(ws + 98304);     // B*L*8 = 256 KB
    int2*  win     = (int2*)(ws + 360448);     // B*MAXTB
    u16*   XcT     = (u16*)(ws + 364544);      // B*E*L bf16 = 8.39 MB

    float* out_up = (float*)d_out;                 // (B,T,E)
    float* out_w  = out_up + (size_t)NB * T * NE;  // (B,L,T)

    k_xc<<<dim3(8, 8, NB), dim3(256), 0, stream>>>(x, en, pt, wn, bn, wq, bq, wproj,
                                                   XcT, dot8);
    k_pre<<<dim3(NB), dim3(512), 0, stream>>>(dint, df, lens, wproj, wd, bd, bproj,
                                              dot8, means, inv_std, Aarr, win, ntb);
    k_gemm<<<dim3(4, ntb, NB), dim3(256), 0, stream>>>(XcT, frames, means, inv_std,
                                                       Aarr, win, out_up, out_w, T);
}

// Round 11
// 56.119 us; speedup vs baseline: 1.5099x; 1.5099x over previous
//
#include <hip/hip_runtime.h>

typedef unsigned short u16;
typedef unsigned int u32;
typedef __attribute__((ext_vector_type(8))) short short8;
typedef __attribute__((ext_vector_type(4))) float f32x4;

#define LOG_SQRT_2PI 0.9189385332046727f
#define NB 16
#define NL 512
#define NE 512
#define ZWIN 20.0f
#define MAXTB 32

__device__ __forceinline__ u16 f2bf(float x) {
    u32 u = __builtin_bit_cast(u32, x);
    u += 0x7fffu + ((u >> 16) & 1u);
    return (u16)(u >> 16);
}

__device__ __forceinline__ void gload_lds16(const u16* g, u16* l) {
    __builtin_amdgcn_global_load_lds(
        (__attribute__((address_space(1))) void*)(u16*)g,
        (__attribute__((address_space(3))) void*)l,
        16, 0, 0);
}

// ---------------- K1: xc -> XcT[b][e][l] bf16 + per-eblock partial dot(xc, wproj) ----------------
// 4 e per thread: float4 x loads, 16-lane dot reduce (f32-exact), 16x less en/pt redundancy
__global__ void k_xc(const float* __restrict__ x, const float* __restrict__ en,
                     const float* __restrict__ pt,
                     const float* __restrict__ wn, const float* __restrict__ bn,
                     const float* __restrict__ wq, const float* __restrict__ bq,
                     const float* __restrict__ wproj,
                     u16* __restrict__ XcT, float* __restrict__ dot8) {
    __shared__ u16 tile[64][68];
    int b = blockIdx.z;
    int l0 = blockIdx.y * 64, e0 = blockIdx.x * 64;
    int tid = threadIdx.x;               // 256
    int c16 = tid & 15, rg = tid >> 4;   // 16 e-groups x 16 row-groups
    int e = e0 + c16 * 4;
    float wnA[12], wqA[12], bias[4], wp[4];
    {
        const float4* p = (const float4*)(wn + (size_t)e * 3);
        float4 a0 = p[0], a1 = p[1], a2 = p[2];
        wnA[0]=a0.x; wnA[1]=a0.y; wnA[2]=a0.z; wnA[3]=a0.w; wnA[4]=a1.x; wnA[5]=a1.y;
        wnA[6]=a1.z; wnA[7]=a1.w; wnA[8]=a2.x; wnA[9]=a2.y; wnA[10]=a2.z; wnA[11]=a2.w;
        const float4* q = (const float4*)(wq + (size_t)e * 3);
        float4 b0 = q[0], b1 = q[1], b2 = q[2];
        wqA[0]=b0.x; wqA[1]=b0.y; wqA[2]=b0.z; wqA[3]=b0.w; wqA[4]=b1.x; wqA[5]=b1.y;
        wqA[6]=b1.z; wqA[7]=b1.w; wqA[8]=b2.x; wqA[9]=b2.y; wqA[10]=b2.z; wqA[11]=b2.w;
        float4 bn4 = *(const float4*)(bn + e);
        float4 bq4 = *(const float4*)(bq + e);
        bias[0]=bn4.x+bq4.x; bias[1]=bn4.y+bq4.y; bias[2]=bn4.z+bq4.z; bias[3]=bn4.w+bq4.w;
        float4 wp4 = *(const float4*)(wproj + e);
        wp[0]=wp4.x; wp[1]=wp4.y; wp[2]=wp4.z; wp[3]=wp4.w;
    }
    int base = b * NL;
    #pragma unroll
    for (int it = 0; it < 4; ++it) {
        int ll = rg + 16 * it;
        int l = l0 + ll;
        float em1 = (l > 0)   ? en[base + l - 1] : 0.f;
        float ev  = en[base + l];
        float ep1 = (l < 511) ? en[base + l + 1] : 0.f;
        float pm1 = (l > 0)   ? pt[base + l - 1] : 0.f;
        float pv  = pt[base + l];
        float pp1 = (l < 511) ? pt[base + l + 1] : 0.f;
        float4 xv = *(const float4*)(x + ((size_t)(base + l)) * NE + e);
        float xa[4] = {xv.x, xv.y, xv.z, xv.w};
        float pd = 0.f;
        #pragma unroll
        for (int k = 0; k < 4; ++k) {
            float v = xa[k]
                    + wnA[k*3+0] * em1 + wnA[k*3+1] * ev + wnA[k*3+2] * ep1
                    + wqA[k*3+0] * pm1 + wqA[k*3+1] * pv + wqA[k*3+2] * pp1 + bias[k];
            tile[ll][c16 * 4 + k] = f2bf(v);
            pd = fmaf(v, wp[k], pd);
        }
        #pragma unroll
        for (int m = 8; m; m >>= 1) pd += __shfl_xor(pd, m);
        if (c16 == 0) dot8[((size_t)(base + l)) * 8 + blockIdx.x] = pd;
    }
    __syncthreads();
    int lr = tid >> 6, c = tid & 63;
    #pragma unroll 4
    for (int it = 0; it < 16; ++it) {
        int eo = lr + 4 * it;  // 0..63
        XcT[((size_t)b * NE + (e0 + eo)) * NL + l0 + c] = tile[c][eo];
    }
}

// ---------------- K2: taps(local) + cumsum means + ranges/inv_std/A + window table ----------------
__global__ void k_pre(const int* __restrict__ dint, const float* __restrict__ df,
                      const int* __restrict__ lens,
                      const float* __restrict__ wproj, const float* __restrict__ wd,
                      const float* __restrict__ bd, const float* __restrict__ bproj,
                      const float* __restrict__ dot8,
                      float* __restrict__ means, float* __restrict__ inv_std,
                      float* __restrict__ Aarr, int2* __restrict__ win, int ntb) {
    int b = blockIdx.x, l = threadIdx.x;  // 512 threads
    __shared__ float s[NL];
    __shared__ float red[4][8];
    __shared__ float tarr[4];
    __shared__ int slo[MAXTB], shi[MAXTB];
    {
        float wp = wproj[l];
        float v[4] = {wp * wd[l * 3 + 0], wp * wd[l * 3 + 1], wp * wd[l * 3 + 2], wp * bd[l]};
        int lane = l & 63, wv = l >> 6;
        #pragma unroll
        for (int i = 0; i < 4; i++) {
            float t = v[i];
            for (int m = 32; m; m >>= 1) t += __shfl_xor(t, m);
            if (lane == 0) red[i][wv] = t;
        }
    }
    if (l < ntb) { slo[l] = NL; shi[l] = -1; }
    float d = (float)dint[b * NL + l];
    s[l] = d;
    __syncthreads();
    if (l < 4) {
        float t = 0.f;
        for (int w2 = 0; w2 < 8; w2++) t += red[l][w2];
        if (l == 3) t += bproj[0];
        tarr[l] = t;
    }
    for (int off = 1; off < NL; off <<= 1) {
        float v = (l >= off) ? s[l - off] : 0.0f;
        __syncthreads();
        s[l] += v;
        __syncthreads();
    }
    float mean = s[l] - 0.5f * d;
    means[b * NL + l] = mean;
    int base = b * NL;
    float dot;
    {
        const float4* dp = (const float4*)(dot8 + ((size_t)(base + l)) * 8);
        float4 a = dp[0], bb4 = dp[1];
        dot = ((a.x + a.y) + (a.z + a.w)) + ((bb4.x + bb4.y) + (bb4.z + bb4.w));
    }
    float dm1 = (l > 0)   ? df[base + l - 1] : 0.f;
    float d0  = df[base + l];
    float dp1 = (l < 511) ? df[base + l + 1] : 0.f;
    float lin = dot + tarr[3]
              + tarr[0] * dm1 + tarr[1] * d0 + tarr[2] * dp1;
    float r = (lin > 20.f) ? lin : log1pf(expf(lin));
    bool pad = (l >= lens[b]);
    if (pad) r = 1.0f;
    float sd = fmaxf(r, 0.001f);
    inv_std[base + l] = 1.0f / sd;
    Aarr[base + l] = pad ? -1e30f : (-logf(sd) - LOG_SQRT_2PI);
    if (!pad) {
        float fl = mean - ZWIN * sd - 1.0f;
        float fh = mean + ZWIN * sd + 1.0f;
        for (int tb = 0; tb < ntb; ++tb) {
            float t_lo = tb * 128.0f + 0.5f, t_hi = tb * 128.0f + 127.5f;
            if (fl <= t_hi && fh >= t_lo) {
                atomicMin(&slo[tb], l);
                atomicMax(&shi[tb], l);
            }
        }
    }
    __syncthreads();
    if (l < ntb) win[b * MAXTB + l] = make_int2(slo[l], shi[l]);
}

// ---------------- K3: banded GEMM; rn in-block; out_w rows split across e-blocks ----------------
__global__ __launch_bounds__(256) void k_gemm(const u16* __restrict__ XcT,
                                              const float* __restrict__ frames,
                                              const float* __restrict__ means,
                                              const float* __restrict__ inv_std,
                                              const float* __restrict__ Aarr,
                                              const int2* __restrict__ win,
                                              float* __restrict__ out,
                                              float* __restrict__ wout, int T) {
    __shared__ float4 sq[NL];
    __shared__ float fts[128];
    __shared__ float part[2][128];
    __shared__ float rvs[128];
    __shared__ u16 At[2][128][32];
    __shared__ u16 Bt[2][128][32];
    int b = blockIdx.z;
    int t0 = blockIdx.y * 128;
    int e0 = blockIdx.x * 128;
    int tid = threadIdx.x;
    int lane = tid & 63, wid = tid >> 6;
    int wm = wid >> 1, wn = wid & 1;
    const u16* Bb = XcT + (size_t)b * NE * NL;

    int2 w = win[b * MAXTB + blockIdx.y];
    int ks0 = 0, nst = 0;
    if (w.x <= w.y) { ks0 = w.x >> 5; nst = (w.y >> 5) - ks0 + 1; }
    int bl0 = ks0 * 32, bl1 = (ks0 + nst) * 32;

    // band-restricted stats load
    for (int i = bl0 + tid; i < bl1; i += 256)
        sq[i] = make_float4(means[b * NL + i], inv_std[b * NL + i], Aarr[b * NL + i], 0.f);
    if (tid < 128) fts[tid] = (t0 + tid < T) ? frames[t0 + tid] : -1e9f;

    __syncthreads();  // sq, fts ready

    // --- per-t normalizer: 2 threads per t sum the band ---
    if (nst > 0) {
        int tr = tid & 127, h = tid >> 7;
        float ftr = fts[tr];
        float ssum = 0.f;
        for (int l = w.x + h; l <= w.y; l += 2) {
            float4 q = sq[l];
            float z = (ftr - q.x) * q.y;
            ssum += __expf(fmaf(z, -0.5f * z, q.z));
        }
        part[h][tr] = ssum;
    }
    __syncthreads();
    if (tid < 128) rvs[tid] = 1.0f / (part[0][tid] + part[1][tid] + 1e-20f);
    __syncthreads();

    int ta = tid >> 1;        // A-row (t offset) this thread fills
    int ha = (tid & 1) * 16;  // which 16-col half
    float ft = fts[ta];
    float rv = rvs[ta];

    int srow = wid * 32 + (lane >> 2);
    int skc = (lane & 3) * 8;

    f32x4 acc[4][4];
    #pragma unroll
    for (int m = 0; m < 4; m++)
        #pragma unroll
        for (int n = 0; n < 4; n++)
            #pragma unroll
            for (int k = 0; k < 4; k++) acc[m][n][k] = 0.0f;

    auto stage = [&](int buf, int ks) {
        int l0 = ks * 32;
        const u16* gb = Bb + (size_t)(e0 + srow) * NL + l0 + skc;
        gload_lds16(gb, &Bt[buf][wid * 32][0]);
        gload_lds16(gb + 16 * NL, &Bt[buf][wid * 32 + 16][0]);
        u32 pk[8];
        #pragma unroll
        for (int jj = 0; jj < 8; ++jj) {
            float4 q0 = sq[l0 + ha + jj * 2];
            float4 q1 = sq[l0 + ha + jj * 2 + 1];
            float z0 = (ft - q0.x) * q0.y;
            float p0 = __expf(fmaf(z0, -0.5f * z0, q0.z)) * rv;
            float z1 = (ft - q1.x) * q1.y;
            float p1 = __expf(fmaf(z1, -0.5f * z1, q1.z)) * rv;
            pk[jj] = (u32)f2bf(p0) | ((u32)f2bf(p1) << 16);
        }
        *(uint4*)&At[buf][ta][ha]     = make_uint4(pk[0], pk[1], pk[2], pk[3]);
        *(uint4*)&At[buf][ta][ha + 8] = make_uint4(pk[4], pk[5], pk[6], pk[7]);
    };

    int fr = lane & 15, fk = (lane >> 4) * 8;
    if (nst > 0) {
        stage(0, ks0);
        for (int s = 0; s < nst; ++s) {
            __syncthreads();  // buf[s&1] (ds_writes + gload_lds) visible
            if (s + 1 < nst) stage((s + 1) & 1, ks0 + s + 1);
            int buf = s & 1;
            short8 a[4], bb[4];
            #pragma unroll
            for (int m = 0; m < 4; m++)
                a[m] = *(const short8*)&At[buf][wm * 64 + m * 16 + fr][fk];
            #pragma unroll
            for (int n = 0; n < 4; n++)
                bb[n] = *(const short8*)&Bt[buf][wn * 64 + n * 16 + fr][fk];
            #pragma unroll
            for (int m = 0; m < 4; m++)
                #pragma unroll
                for (int n = 0; n < 4; n++)
                    acc[m][n] = __builtin_amdgcn_mfma_f32_16x16x32_bf16(a[m], bb[n], acc[m][n], 0, 0, 0);
        }
    }

    // --- C-write ---
    int r4 = (lane >> 4) * 4;
    #pragma unroll
    for (int m = 0; m < 4; m++) {
        int tb2 = t0 + wm * 64 + m * 16 + r4;
        #pragma unroll
        for (int j = 0; j < 4; j++) {
            int t = tb2 + j;
            if (t < T) {
                float* orow = out + ((size_t)b * T + t) * NE + e0 + wn * 64 + (lane & 15);
                #pragma unroll
                for (int n = 0; n < 4; n++) orow[n * 16] = acc[m][n][j];
            }
        }
    }

    // --- out_w epilogue: this e-block writes rows [e0, e0+128), lane <-> t coalesced ---
    if (t0 < T) {
        int tcnt = T - t0; if (tcnt > 128) tcnt = 128;
        int rbeg = e0, rend = e0 + 128;
        int ib0 = bl0 > rbeg ? bl0 : rbeg;
        int ib1 = bl1 < rend ? bl1 : rend;
        int t4 = (tid & 31) * 4, rsub = tid >> 5;     // 8 rows per pass
        bool t4full = (t4 + 4 <= tcnt);
        float4 z4 = make_float4(0.f, 0.f, 0.f, 0.f);
        auto zfill = [&](int r0, int r1) {
            for (int l = r0 + rsub; l < r1; l += 8) {
                float* d = wout + ((size_t)b * NL + l) * T + t0 + t4;
                if (t4full) *(float4*)d = z4;
                else { for (int u = 0; u < 4 && t4 + u < tcnt; ++u) d[u] = 0.f; }
            }
        };
        if (ib0 >= ib1) {
            zfill(rbeg, rend);
        } else {
            zfill(rbeg, ib0);
            zfill(ib1, rend);
            int tt = tid & 127, half = tid >> 7;
            if (tt < tcnt) {
                float ftl = fts[tt], rvl = rvs[tt];
                float* dstc = wout + (size_t)b * NL * T + t0 + tt;
                for (int l = ib0 + half; l < ib1; l += 2) {
                    float4 q = sq[l];
                    float z = (ftl - q.x) * q.y;
                    dstc[(size_t)l * T] = __expf(fmaf(z, -0.5f * z, q.z)) * rvl;
                }
            }
        }
    }
}

extern "C" void kernel_launch(void* const* d_in, const int* in_sizes, int n_in,
                              void* d_out, int out_size, void* d_ws, size_t ws_size,
                              hipStream_t stream) {
    const float* x      = (const float*)d_in[0];
    const float* df     = (const float*)d_in[1];
    const int*   dint   = (const int*)d_in[2];
    const float* en     = (const float*)d_in[3];
    const float* pt     = (const float*)d_in[4];
    const int*   lens   = (const int*)d_in[5];
    const float* frames = (const float*)d_in[6];
    const float* wd     = (const float*)d_in[7];
    const float* bd     = (const float*)d_in[8];
    const float* wn     = (const float*)d_in[9];
    const float* bn     = (const float*)d_in[10];
    const float* wq     = (const float*)d_in[11];
    const float* bq     = (const float*)d_in[12];
    const float* wproj  = (const float*)d_in[13];
    const float* bproj  = (const float*)d_in[14];

    int T = in_sizes[6];
    int ntb = (T + 127) / 128;   // <= 32

    char* ws = (char*)d_ws;
    float* means   = (float*)(ws);             // B*L
    float* inv_std = (float*)(ws + 32768);     // B*L
    float* Aarr    = (float*)(ws + 65536);     // B*L
    float* dot8    = (float*)(ws + 98304);     // B*L*8 = 256 KB
    int2*  win     = (int2*)(ws + 360448);     // B*MAXTB
    u16*   XcT     = (u16*)(ws + 364544);      // B*E*L bf16 = 8.39 MB

    float* out_up = (float*)d_out;                 // (B,T,E)
    float* out_w  = out_up + (size_t)NB * T * NE;  // (B,L,T)

    k_xc<<<dim3(8, 8, NB), dim3(256), 0, stream>>>(x, en, pt, wn, bn, wq, bq, wproj,
                                                   XcT, dot8);
    k_pre<<<dim3(NB), dim3(512), 0, stream>>>(dint, df, lens, wproj, wd, bd, bproj,
                                              dot8, means, inv_std, Aarr, win, ntb);
    k_gemm<<<dim3(4, ntb, NB), dim3(256), 0, stream>>>(XcT, frames, means, inv_std,
                                                       Aarr, win, out_up, out_w, T);
}

// Round 12
// 55.224 us; speedup vs baseline: 1.5344x; 1.0162x over previous
//
#include <hip/hip_runtime.h>

typedef unsigned short u16;
typedef unsigned int u32;
typedef __attribute__((ext_vector_type(8))) short short8;
typedef __attribute__((ext_vector_type(4))) float f32x4;

#define LOG_SQRT_2PI 0.9189385332046727f
#define NB 16
#define NL 512
#define NE 512
#define ZWIN 20.0f
#define MAXTB 32

__device__ __forceinline__ u16 f2bf(float x) {
    u32 u = __builtin_bit_cast(u32, x);
    u += 0x7fffu + ((u >> 16) & 1u);
    return (u16)(u >> 16);
}

__device__ __forceinline__ void gload_lds16(const u16* g, u16* l) {
    __builtin_amdgcn_global_load_lds(
        (__attribute__((address_space(1))) void*)(u16*)g,
        (__attribute__((address_space(3))) void*)l,
        16, 0, 0);
}

// ---------------- K1: xc -> XcT[b][e][l] bf16 + per-eblock partial dot(xc, wproj) ----------------
// 4 e per thread: float4 x loads, 16-lane dot reduce (f32-exact), 16x less en/pt redundancy
__global__ void k_xc(const float* __restrict__ x, const float* __restrict__ en,
                     const float* __restrict__ pt,
                     const float* __restrict__ wn, const float* __restrict__ bn,
                     const float* __restrict__ wq, const float* __restrict__ bq,
                     const float* __restrict__ wproj,
                     u16* __restrict__ XcT, float* __restrict__ dot8) {
    __shared__ u16 tile[64][68];
    int b = blockIdx.z;
    int l0 = blockIdx.y * 64, e0 = blockIdx.x * 64;
    int tid = threadIdx.x;               // 256
    int c16 = tid & 15, rg = tid >> 4;   // 16 e-groups x 16 row-groups
    int e = e0 + c16 * 4;
    float wnA[12], wqA[12], bias[4], wp[4];
    {
        const float4* p = (const float4*)(wn + (size_t)e * 3);
        float4 a0 = p[0], a1 = p[1], a2 = p[2];
        wnA[0]=a0.x; wnA[1]=a0.y; wnA[2]=a0.z; wnA[3]=a0.w; wnA[4]=a1.x; wnA[5]=a1.y;
        wnA[6]=a1.z; wnA[7]=a1.w; wnA[8]=a2.x; wnA[9]=a2.y; wnA[10]=a2.z; wnA[11]=a2.w;
        const float4* q = (const float4*)(wq + (size_t)e * 3);
        float4 b0 = q[0], b1 = q[1], b2 = q[2];
        wqA[0]=b0.x; wqA[1]=b0.y; wqA[2]=b0.z; wqA[3]=b0.w; wqA[4]=b1.x; wqA[5]=b1.y;
        wqA[6]=b1.z; wqA[7]=b1.w; wqA[8]=b2.x; wqA[9]=b2.y; wqA[10]=b2.z; wqA[11]=b2.w;
        float4 bn4 = *(const float4*)(bn + e);
        float4 bq4 = *(const float4*)(bq + e);
        bias[0]=bn4.x+bq4.x; bias[1]=bn4.y+bq4.y; bias[2]=bn4.z+bq4.z; bias[3]=bn4.w+bq4.w;
        float4 wp4 = *(const float4*)(wproj + e);
        wp[0]=wp4.x; wp[1]=wp4.y; wp[2]=wp4.z; wp[3]=wp4.w;
    }
    int base = b * NL;
    #pragma unroll
    for (int it = 0; it < 4; ++it) {
        int ll = rg + 16 * it;
        int l = l0 + ll;
        float em1 = (l > 0)   ? en[base + l - 1] : 0.f;
        float ev  = en[base + l];
        float ep1 = (l < 511) ? en[base + l + 1] : 0.f;
        float pm1 = (l > 0)   ? pt[base + l - 1] : 0.f;
        float pv  = pt[base + l];
        float pp1 = (l < 511) ? pt[base + l + 1] : 0.f;
        float4 xv = *(const float4*)(x + ((size_t)(base + l)) * NE + e);
        float xa[4] = {xv.x, xv.y, xv.z, xv.w};
        float pd = 0.f;
        #pragma unroll
        for (int k = 0; k < 4; ++k) {
            float v = xa[k]
                    + wnA[k*3+0] * em1 + wnA[k*3+1] * ev + wnA[k*3+2] * ep1
                    + wqA[k*3+0] * pm1 + wqA[k*3+1] * pv + wqA[k*3+2] * pp1 + bias[k];
            tile[ll][c16 * 4 + k] = f2bf(v);
            pd = fmaf(v, wp[k], pd);
        }
        #pragma unroll
        for (int m = 8; m; m >>= 1) pd += __shfl_xor(pd, m);
        if (c16 == 0) dot8[((size_t)(base + l)) * 8 + blockIdx.x] = pd;
    }
    __syncthreads();
    int lr = tid >> 6, c = tid & 63;
    #pragma unroll 4
    for (int it = 0; it < 16; ++it) {
        int eo = lr + 4 * it;  // 0..63
        XcT[((size_t)b * NE + (e0 + eo)) * NL + l0 + c] = tile[c][eo];
    }
}

// ---------------- K2: taps(local) + cumsum means + ranges/inv_std/A + window table ----------------
__global__ void k_pre(const int* __restrict__ dint, const float* __restrict__ df,
                      const int* __restrict__ lens,
                      const float* __restrict__ wproj, const float* __restrict__ wd,
                      const float* __restrict__ bd, const float* __restrict__ bproj,
                      const float* __restrict__ dot8,
                      float* __restrict__ means, float* __restrict__ inv_std,
                      float* __restrict__ Aarr, int2* __restrict__ win, int ntb) {
    int b = blockIdx.x, l = threadIdx.x;  // 512 threads
    __shared__ float s[NL];
    __shared__ float red[4][8];
    __shared__ float tarr[4];
    __shared__ int slo[MAXTB], shi[MAXTB];
    {
        float wp = wproj[l];
        float v[4] = {wp * wd[l * 3 + 0], wp * wd[l * 3 + 1], wp * wd[l * 3 + 2], wp * bd[l]};
        int lane = l & 63, wv = l >> 6;
        #pragma unroll
        for (int i = 0; i < 4; i++) {
            float t = v[i];
            for (int m = 32; m; m >>= 1) t += __shfl_xor(t, m);
            if (lane == 0) red[i][wv] = t;
        }
    }
    if (l < ntb) { slo[l] = NL; shi[l] = -1; }
    float d = (float)dint[b * NL + l];
    s[l] = d;
    __syncthreads();
    if (l < 4) {
        float t = 0.f;
        for (int w2 = 0; w2 < 8; w2++) t += red[l][w2];
        if (l == 3) t += bproj[0];
        tarr[l] = t;
    }
    for (int off = 1; off < NL; off <<= 1) {
        float v = (l >= off) ? s[l - off] : 0.0f;
        __syncthreads();
        s[l] += v;
        __syncthreads();
    }
    float mean = s[l] - 0.5f * d;
    means[b * NL + l] = mean;
    int base = b * NL;
    float dot;
    {
        const float4* dp = (const float4*)(dot8 + ((size_t)(base + l)) * 8);
        float4 a = dp[0], bb4 = dp[1];
        dot = ((a.x + a.y) + (a.z + a.w)) + ((bb4.x + bb4.y) + (bb4.z + bb4.w));
    }
    float dm1 = (l > 0)   ? df[base + l - 1] : 0.f;
    float d0  = df[base + l];
    float dp1 = (l < 511) ? df[base + l + 1] : 0.f;
    float lin = dot + tarr[3]
              + tarr[0] * dm1 + tarr[1] * d0 + tarr[2] * dp1;
    float r = (lin > 20.f) ? lin : log1pf(expf(lin));
    bool pad = (l >= lens[b]);
    if (pad) r = 1.0f;
    float sd = fmaxf(r, 0.001f);
    inv_std[base + l] = 1.0f / sd;
    Aarr[base + l] = pad ? -1e30f : (-logf(sd) - LOG_SQRT_2PI);
    if (!pad) {
        float fl = mean - ZWIN * sd - 1.0f;
        float fh = mean + ZWIN * sd + 1.0f;
        for (int tb = 0; tb < ntb; ++tb) {
            float t_lo = tb * 128.0f + 0.5f, t_hi = tb * 128.0f + 127.5f;
            if (fl <= t_hi && fh >= t_lo) {
                atomicMin(&slo[tb], l);
                atomicMax(&shi[tb], l);
            }
        }
    }
    __syncthreads();
    if (l < ntb) win[b * MAXTB + l] = make_int2(slo[l], shi[l]);
}

// ---------------- K3: banded GEMM; rn in-block; early-issue out_w stores; 40KB LDS ----------------
__global__ __launch_bounds__(256) void k_gemm(const u16* __restrict__ XcT,
                                              const float* __restrict__ frames,
                                              const float* __restrict__ means,
                                              const float* __restrict__ inv_std,
                                              const float* __restrict__ Aarr,
                                              const int2* __restrict__ win,
                                              float* __restrict__ out,
                                              float* __restrict__ wout, int T) {
    __shared__ float sm[NL], si[NL], sa[NL];   // 6 KB (was float4: 8 KB)
    __shared__ float fts[128];
    __shared__ float part[2][128];
    __shared__ float rvs[128];
    __shared__ u16 At[2][128][32];
    __shared__ u16 Bt[2][128][32];
    int b = blockIdx.z;
    int t0 = blockIdx.y * 128;
    int e0 = blockIdx.x * 128;
    int tid = threadIdx.x;
    int lane = tid & 63, wid = tid >> 6;
    int wm = wid >> 1, wn = wid & 1;
    const u16* Bb = XcT + (size_t)b * NE * NL;

    int2 w = win[b * MAXTB + blockIdx.y];
    int ks0 = 0, nst = 0;
    if (w.x <= w.y) { ks0 = w.x >> 5; nst = (w.y >> 5) - ks0 + 1; }
    int bl0 = ks0 * 32, bl1 = (ks0 + nst) * 32;

    // --- out_w zero-fill FIRST (depends only on win): stores drain under later compute ---
    int tcnt = T - t0; if (tcnt > 128) tcnt = 128;
    int rbeg = e0, rend = e0 + 128;
    int ib0 = bl0 > rbeg ? bl0 : rbeg;
    int ib1 = bl1 < rend ? bl1 : rend;
    {
        int t4 = (tid & 31) * 4, rsub = tid >> 5;  // 8 rows per pass, float4 across t
        bool t4full = (t4 + 4 <= tcnt);
        float4 z4 = make_float4(0.f, 0.f, 0.f, 0.f);
        auto zfill = [&](int r0, int r1) {
            for (int l = r0 + rsub; l < r1; l += 8) {
                float* d = wout + ((size_t)b * NL + l) * T + t0 + t4;
                if (t4full) *(float4*)d = z4;
                else { for (int u = 0; u < 4 && t4 + u < tcnt; ++u) d[u] = 0.f; }
            }
        };
        if (ib0 >= ib1) zfill(rbeg, rend);
        else { zfill(rbeg, ib0); zfill(ib1, rend); }
    }

    // band-restricted stats load
    for (int i = bl0 + tid; i < bl1; i += 256) {
        sm[i] = means[b * NL + i];
        si[i] = inv_std[b * NL + i];
        sa[i] = Aarr[b * NL + i];
    }
    if (tid < 128) fts[tid] = (t0 + tid < T) ? frames[t0 + tid] : -1e9f;

    __syncthreads();  // sm/si/sa, fts ready

    // --- per-t normalizer: 2 threads per t sum the band ---
    if (nst > 0) {
        int tr = tid & 127, h = tid >> 7;
        float ftr = fts[tr];
        float ssum = 0.f;
        for (int l = w.x + h; l <= w.y; l += 2) {
            float z = (ftr - sm[l]) * si[l];
            ssum += __expf(fmaf(z, -0.5f * z, sa[l]));
        }
        part[h][tr] = ssum;
    }
    __syncthreads();
    if (tid < 128) rvs[tid] = 1.0f / (part[0][tid] + part[1][tid] + 1e-20f);
    __syncthreads();

    // --- in-band out_w rows (needs rvs): issue BEFORE the MFMA loop ---
    if (ib0 < ib1) {
        int tt = tid & 127, half = tid >> 7;
        if (tt < tcnt) {
            float ftl = fts[tt], rvl = rvs[tt];
            float* dstc = wout + (size_t)b * NL * T + t0 + tt;
            for (int l = ib0 + half; l < ib1; l += 2) {
                float z = (ftl - sm[l]) * si[l];
                dstc[(size_t)l * T] = __expf(fmaf(z, -0.5f * z, sa[l])) * rvl;
            }
        }
    }

    int ta = tid >> 1;        // A-row (t offset) this thread fills
    int ha = (tid & 1) * 16;  // which 16-col half
    float ft = fts[ta];
    float rv = rvs[ta];

    int srow = wid * 32 + (lane >> 2);
    int skc = (lane & 3) * 8;

    f32x4 acc[4][4];
    #pragma unroll
    for (int m = 0; m < 4; m++)
        #pragma unroll
        for (int n = 0; n < 4; n++)
            #pragma unroll
            for (int k = 0; k < 4; k++) acc[m][n][k] = 0.0f;

    auto stage = [&](int buf, int ks) {
        int l0 = ks * 32;
        const u16* gb = Bb + (size_t)(e0 + srow) * NL + l0 + skc;
        gload_lds16(gb, &Bt[buf][wid * 32][0]);
        gload_lds16(gb + 16 * NL, &Bt[buf][wid * 32 + 16][0]);
        u32 pk[8];
        #pragma unroll
        for (int jj = 0; jj < 8; ++jj) {
            int l0j = l0 + ha + jj * 2;
            float z0 = (ft - sm[l0j]) * si[l0j];
            float p0 = __expf(fmaf(z0, -0.5f * z0, sa[l0j])) * rv;
            float z1 = (ft - sm[l0j + 1]) * si[l0j + 1];
            float p1 = __expf(fmaf(z1, -0.5f * z1, sa[l0j + 1])) * rv;
            pk[jj] = (u32)f2bf(p0) | ((u32)f2bf(p1) << 16);
        }
        *(uint4*)&At[buf][ta][ha]     = make_uint4(pk[0], pk[1], pk[2], pk[3]);
        *(uint4*)&At[buf][ta][ha + 8] = make_uint4(pk[4], pk[5], pk[6], pk[7]);
    };

    int fr = lane & 15, fk = (lane >> 4) * 8;
    if (nst > 0) {
        stage(0, ks0);
        for (int s = 0; s < nst; ++s) {
            __syncthreads();  // buf[s&1] (ds_writes + gload_lds) visible
            if (s + 1 < nst) stage((s + 1) & 1, ks0 + s + 1);
            int buf = s & 1;
            short8 a[4], bb[4];
            #pragma unroll
            for (int m = 0; m < 4; m++)
                a[m] = *(const short8*)&At[buf][wm * 64 + m * 16 + fr][fk];
            #pragma unroll
            for (int n = 0; n < 4; n++)
                bb[n] = *(const short8*)&Bt[buf][wn * 64 + n * 16 + fr][fk];
            #pragma unroll
            for (int m = 0; m < 4; m++)
                #pragma unroll
                for (int n = 0; n < 4; n++)
                    acc[m][n] = __builtin_amdgcn_mfma_f32_16x16x32_bf16(a[m], bb[n], acc[m][n], 0, 0, 0);
        }
    }

    // --- C-write ---
    int r4 = (lane >> 4) * 4;
    #pragma unroll
    for (int m = 0; m < 4; m++) {
        int tb2 = t0 + wm * 64 + m * 16 + r4;
        #pragma unroll
        for (int j = 0; j < 4; j++) {
            int t = tb2 + j;
            if (t < T) {
                float* orow = out + ((size_t)b * T + t) * NE + e0 + wn * 64 + (lane & 15);
                #pragma unroll
                for (int n = 0; n < 4; n++) orow[n * 16] = acc[m][n][j];
            }
        }
    }
}

extern "C" void kernel_launch(void* const* d_in, const int* in_sizes, int n_in,
                              void* d_out, int out_size, void* d_ws, size_t ws_size,
                              hipStream_t stream) {
    const float* x      = (const float*)d_in[0];
    const float* df     = (const float*)d_in[1];
    const int*   dint   = (const int*)d_in[2];
    const float* en     = (const float*)d_in[3];
    const float* pt     = (const float*)d_in[4];
    const int*   lens   = (const int*)d_in[5];
    const float* frames = (const float*)d_in[6];
    const float* wd     = (const float*)d_in[7];
    const float* bd     = (const float*)d_in[8];
    const float* wn     = (const float*)d_in[9];
    const float* bn     = (const float*)d_in[10];
    const float* wq     = (const float*)d_in[11];
    const float* bq     = (const float*)d_in[12];
    const float* wproj  = (const float*)d_in[13];
    const float* bproj  = (const float*)d_in[14];

    int T = in_sizes[6];
    int ntb = (T + 127) / 128;   // <= 32

    char* ws = (char*)d_ws;
    float* means   = (float*)(ws);             // B*L
    float* inv_std = (float*)(ws + 32768);     // B*L
    float* Aarr    = (float*)(ws + 65536);     // B*L
    float* dot8    = (float*)(ws + 98304);     // B*L*8 = 256 KB
    int2*  win     = (int2*)(ws + 360448);     // B*MAXTB
    u16*   XcT     = (u16*)(ws + 364544);      // B*E*L bf16 = 8.39 MB

    float* out_up = (float*)d_out;                 // (B,T,E)
    float* out_w  = out_up + (size_t)NB * T * NE;  // (B,L,T)

    k_xc<<<dim3(8, 8, NB), dim3(256), 0, stream>>>(x, en, pt, wn, bn, wq, bq, wproj,
                                                   XcT, dot8);
    k_pre<<<dim3(NB), dim3(512), 0, stream>>>(dint, df, lens, wproj, wd, bd, bproj,
                                              dot8, means, inv_std, Aarr, win, ntb);
    k_gemm<<<dim3(4, ntb, NB), dim3(256), 0, stream>>>(XcT, frames, means, inv_std,
                                                       Aarr, win, out_up, out_w, T);
}

// Round 13
// 54.573 us; speedup vs baseline: 1.5527x; 1.0119x over previous
//
#include <hip/hip_runtime.h>

typedef unsigned short u16;
typedef unsigned int u32;
typedef __attribute__((ext_vector_type(8))) short short8;
typedef __attribute__((ext_vector_type(4))) float f32x4;

#define LOG_SQRT_2PI 0.9189385332046727f
#define NB 16
#define NL 512
#define NE 512
#define ZWIN 20.0f
#define MAXTB 32

__device__ __forceinline__ u16 f2bf(float x) {
    u32 u = __builtin_bit_cast(u32, x);
    u += 0x7fffu + ((u >> 16) & 1u);
    return (u16)(u >> 16);
}

__device__ __forceinline__ void gload_lds16(const u16* g, u16* l) {
    __builtin_amdgcn_global_load_lds(
        (__attribute__((address_space(1))) void*)(u16*)g,
        (__attribute__((address_space(3))) void*)l,
        16, 0, 0);
}

// ---------------- K1: xc -> XcT[b][e][l] bf16 + per-eblock partial dot(xc, wproj) ----------------
__global__ void k_xc(const float* __restrict__ x, const float* __restrict__ en,
                     const float* __restrict__ pt,
                     const float* __restrict__ wn, const float* __restrict__ bn,
                     const float* __restrict__ wq, const float* __restrict__ bq,
                     const float* __restrict__ wproj,
                     u16* __restrict__ XcT, float* __restrict__ dot8) {
    __shared__ u16 tile[64][68];
    int b = blockIdx.z;
    int l0 = blockIdx.y * 64, e0 = blockIdx.x * 64;
    int tid = threadIdx.x;               // 256
    int c16 = tid & 15, rg = tid >> 4;   // 16 e-groups x 16 row-groups
    int e = e0 + c16 * 4;
    float wnA[12], wqA[12], bias[4], wp[4];
    {
        const float4* p = (const float4*)(wn + (size_t)e * 3);
        float4 a0 = p[0], a1 = p[1], a2 = p[2];
        wnA[0]=a0.x; wnA[1]=a0.y; wnA[2]=a0.z; wnA[3]=a0.w; wnA[4]=a1.x; wnA[5]=a1.y;
        wnA[6]=a1.z; wnA[7]=a1.w; wnA[8]=a2.x; wnA[9]=a2.y; wnA[10]=a2.z; wnA[11]=a2.w;
        const float4* q = (const float4*)(wq + (size_t)e * 3);
        float4 b0 = q[0], b1 = q[1], b2 = q[2];
        wqA[0]=b0.x; wqA[1]=b0.y; wqA[2]=b0.z; wqA[3]=b0.w; wqA[4]=b1.x; wqA[5]=b1.y;
        wqA[6]=b1.z; wqA[7]=b1.w; wqA[8]=b2.x; wqA[9]=b2.y; wqA[10]=b2.z; wqA[11]=b2.w;
        float4 bn4 = *(const float4*)(bn + e);
        float4 bq4 = *(const float4*)(bq + e);
        bias[0]=bn4.x+bq4.x; bias[1]=bn4.y+bq4.y; bias[2]=bn4.z+bq4.z; bias[3]=bn4.w+bq4.w;
        float4 wp4 = *(const float4*)(wproj + e);
        wp[0]=wp4.x; wp[1]=wp4.y; wp[2]=wp4.z; wp[3]=wp4.w;
    }
    int base = b * NL;
    #pragma unroll
    for (int it = 0; it < 4; ++it) {
        int ll = rg + 16 * it;
        int l = l0 + ll;
        float em1 = (l > 0)   ? en[base + l - 1] : 0.f;
        float ev  = en[base + l];
        float ep1 = (l < 511) ? en[base + l + 1] : 0.f;
        float pm1 = (l > 0)   ? pt[base + l - 1] : 0.f;
        float pv  = pt[base + l];
        float pp1 = (l < 511) ? pt[base + l + 1] : 0.f;
        float4 xv = *(const float4*)(x + ((size_t)(base + l)) * NE + e);
        float xa[4] = {xv.x, xv.y, xv.z, xv.w};
        float pd = 0.f;
        #pragma unroll
        for (int k = 0; k < 4; ++k) {
            float v = xa[k]
                    + wnA[k*3+0] * em1 + wnA[k*3+1] * ev + wnA[k*3+2] * ep1
                    + wqA[k*3+0] * pm1 + wqA[k*3+1] * pv + wqA[k*3+2] * pp1 + bias[k];
            tile[ll][c16 * 4 + k] = f2bf(v);
            pd = fmaf(v, wp[k], pd);
        }
        #pragma unroll
        for (int m = 8; m; m >>= 1) pd += __shfl_xor(pd, m);
        if (c16 == 0) dot8[((size_t)(base + l)) * 8 + blockIdx.x] = pd;
    }
    __syncthreads();
    int lr = tid >> 6, c = tid & 63;
    #pragma unroll 4
    for (int it = 0; it < 16; ++it) {
        int eo = lr + 4 * it;  // 0..63
        XcT[((size_t)b * NE + (e0 + eo)) * NL + l0 + c] = tile[c][eo];
    }
}

// ---------------- K2: taps(local) + cumsum means + ranges/inv_std/A + window table ----------------
__global__ void k_pre(const int* __restrict__ dint, const float* __restrict__ df,
                      const int* __restrict__ lens,
                      const float* __restrict__ wproj, const float* __restrict__ wd,
                      const float* __restrict__ bd, const float* __restrict__ bproj,
                      const float* __restrict__ dot8,
                      float* __restrict__ means, float* __restrict__ inv_std,
                      float* __restrict__ Aarr, int2* __restrict__ win, int ntb) {
    int b = blockIdx.x, l = threadIdx.x;  // 512 threads
    __shared__ float s[NL];
    __shared__ float red[4][8];
    __shared__ float tarr[4];
    __shared__ int slo[MAXTB], shi[MAXTB];
    {
        float wp = wproj[l];
        float v[4] = {wp * wd[l * 3 + 0], wp * wd[l * 3 + 1], wp * wd[l * 3 + 2], wp * bd[l]};
        int lane = l & 63, wv = l >> 6;
        #pragma unroll
        for (int i = 0; i < 4; i++) {
            float t = v[i];
            for (int m = 32; m; m >>= 1) t += __shfl_xor(t, m);
            if (lane == 0) red[i][wv] = t;
        }
    }
    if (l < ntb) { slo[l] = NL; shi[l] = -1; }
    float d = (float)dint[b * NL + l];
    s[l] = d;
    __syncthreads();
    if (l < 4) {
        float t = 0.f;
        for (int w2 = 0; w2 < 8; w2++) t += red[l][w2];
        if (l == 3) t += bproj[0];
        tarr[l] = t;
    }
    for (int off = 1; off < NL; off <<= 1) {
        float v = (l >= off) ? s[l - off] : 0.0f;
        __syncthreads();
        s[l] += v;
        __syncthreads();
    }
    float mean = s[l] - 0.5f * d;
    means[b * NL + l] = mean;
    int base = b * NL;
    float dot;
    {
        const float4* dp = (const float4*)(dot8 + ((size_t)(base + l)) * 8);
        float4 a = dp[0], bb4 = dp[1];
        dot = ((a.x + a.y) + (a.z + a.w)) + ((bb4.x + bb4.y) + (bb4.z + bb4.w));
    }
    float dm1 = (l > 0)   ? df[base + l - 1] : 0.f;
    float d0  = df[base + l];
    float dp1 = (l < 511) ? df[base + l + 1] : 0.f;
    float lin = dot + tarr[3]
              + tarr[0] * dm1 + tarr[1] * d0 + tarr[2] * dp1;
    float r = (lin > 20.f) ? lin : log1pf(expf(lin));
    bool pad = (l >= lens[b]);
    if (pad) r = 1.0f;
    float sd = fmaxf(r, 0.001f);
    inv_std[base + l] = 1.0f / sd;
    Aarr[base + l] = pad ? -1e30f : (-logf(sd) - LOG_SQRT_2PI);
    if (!pad) {
        float fl = mean - ZWIN * sd - 1.0f;
        float fh = mean + ZWIN * sd + 1.0f;
        for (int tb = 0; tb < ntb; ++tb) {
            float t_lo = tb * 128.0f + 0.5f, t_hi = tb * 128.0f + 127.5f;
            if (fl <= t_hi && fh >= t_lo) {
                atomicMin(&slo[tb], l);
                atomicMax(&shi[tb], l);
            }
        }
    }
    __syncthreads();
    if (l < ntb) win[b * MAXTB + l] = make_int2(slo[l], shi[l]);
}

// ---------------- K3: banded GEMM on UNNORMALIZED P; rn folded into C-write ----------------
__global__ __launch_bounds__(256) void k_gemm(const u16* __restrict__ XcT,
                                              const float* __restrict__ frames,
                                              const float* __restrict__ means,
                                              const float* __restrict__ inv_std,
                                              const float* __restrict__ Aarr,
                                              const int2* __restrict__ win,
                                              float* __restrict__ out,
                                              float* __restrict__ wout, int T) {
    __shared__ float sm[NL], si[NL], sa[NL];
    __shared__ float fts[128];
    __shared__ float part[2][128];
    __shared__ float rvs[128];
    __shared__ u16 At[2][128][32];
    __shared__ u16 Bt[2][128][32];
    int b = blockIdx.z;
    int t0 = blockIdx.y * 128;
    int e0 = blockIdx.x * 128;
    int tid = threadIdx.x;
    int lane = tid & 63, wid = tid >> 6;
    int wm = wid >> 1, wn = wid & 1;
    const u16* Bb = XcT + (size_t)b * NE * NL;

    int2 w = win[b * MAXTB + blockIdx.y];
    int ks0 = 0, nst = 0;
    if (w.x <= w.y) { ks0 = w.x >> 5; nst = (w.y >> 5) - ks0 + 1; }
    int bl0 = ks0 * 32, bl1 = (ks0 + nst) * 32;

    // --- out_w zero-fill FIRST (depends only on win): stores drain under later compute ---
    int tcnt = T - t0; if (tcnt > 128) tcnt = 128;
    int rbeg = e0, rend = e0 + 128;
    int ib0 = bl0 > rbeg ? bl0 : rbeg;
    int ib1 = bl1 < rend ? bl1 : rend;
    {
        int t4 = (tid & 31) * 4, rsub = tid >> 5;  // 8 rows per pass, float4 across t
        bool t4full = (t4 + 4 <= tcnt);
        float4 z4 = make_float4(0.f, 0.f, 0.f, 0.f);
        auto zfill = [&](int r0, int r1) {
            for (int l = r0 + rsub; l < r1; l += 8) {
                float* d = wout + ((size_t)b * NL + l) * T + t0 + t4;
                if (t4full) *(float4*)d = z4;
                else { for (int u = 0; u < 4 && t4 + u < tcnt; ++u) d[u] = 0.f; }
            }
        };
        if (ib0 >= ib1) zfill(rbeg, rend);
        else { zfill(rbeg, ib0); zfill(ib1, rend); }
    }

    // band-restricted stats load
    for (int i = bl0 + tid; i < bl1; i += 256) {
        sm[i] = means[b * NL + i];
        si[i] = inv_std[b * NL + i];
        sa[i] = Aarr[b * NL + i];
    }
    if (tid < 128) fts[tid] = (t0 + tid < T) ? frames[t0 + tid] : -1e9f;

    __syncthreads();  // sm/si/sa, fts ready

    int ta = tid >> 1;        // A-row (t offset) this thread fills
    int ha = (tid & 1) * 16;  // which 16-col half
    float ft = fts[ta];
    float bsum = 0.f;         // this thread's share of row ta's band sum

    int srow = wid * 32 + (lane >> 2);
    int skc = (lane & 3) * 8;

    f32x4 acc[4][4];
    #pragma unroll
    for (int m = 0; m < 4; m++)
        #pragma unroll
        for (int n = 0; n < 4; n++)
            #pragma unroll
            for (int k = 0; k < 4; k++) acc[m][n][k] = 0.0f;

    auto stage = [&](int buf, int ks) {
        int l0 = ks * 32;
        const u16* gb = Bb + (size_t)(e0 + srow) * NL + l0 + skc;
        gload_lds16(gb, &Bt[buf][wid * 32][0]);
        gload_lds16(gb + 16 * NL, &Bt[buf][wid * 32 + 16][0]);
        u32 pk[8];
        #pragma unroll
        for (int jj = 0; jj < 8; ++jj) {
            int l0j = l0 + ha + jj * 2;
            float z0 = (ft - sm[l0j]) * si[l0j];
            float p0 = __expf(fmaf(z0, -0.5f * z0, sa[l0j]));
            float z1 = (ft - sm[l0j + 1]) * si[l0j + 1];
            float p1 = __expf(fmaf(z1, -0.5f * z1, sa[l0j + 1]));
            bsum += p0 + p1;
            pk[jj] = (u32)f2bf(p0) | ((u32)f2bf(p1) << 16);
        }
        *(uint4*)&At[buf][ta][ha]     = make_uint4(pk[0], pk[1], pk[2], pk[3]);
        *(uint4*)&At[buf][ta][ha + 8] = make_uint4(pk[4], pk[5], pk[6], pk[7]);
    };

    int fr = lane & 15, fk = (lane >> 4) * 8;
    if (nst > 0) {
        stage(0, ks0);
        for (int s = 0; s < nst; ++s) {
            __syncthreads();  // buf[s&1] (ds_writes + gload_lds) visible
            if (s + 1 < nst) stage((s + 1) & 1, ks0 + s + 1);
            int buf = s & 1;
            short8 a[4], bb[4];
            #pragma unroll
            for (int m = 0; m < 4; m++)
                a[m] = *(const short8*)&At[buf][wm * 64 + m * 16 + fr][fk];
            #pragma unroll
            for (int n = 0; n < 4; n++)
                bb[n] = *(const short8*)&Bt[buf][wn * 64 + n * 16 + fr][fk];
            #pragma unroll
            for (int m = 0; m < 4; m++)
                #pragma unroll
                for (int n = 0; n < 4; n++)
                    acc[m][n] = __builtin_amdgcn_mfma_f32_16x16x32_bf16(a[m], bb[n], acc[m][n], 0, 0, 0);
        }
    }

    // --- combine band sums -> rvs (free: exps were computed for At anyway) ---
    part[tid & 1][ta] = bsum;
    __syncthreads();
    if (tid < 128) rvs[tid] = 1.0f / (part[0][tid] + part[1][tid] + 1e-20f);
    __syncthreads();

    // --- C-write, scaled by rn[t] ---
    int r4 = (lane >> 4) * 4;
    #pragma unroll
    for (int m = 0; m < 4; m++) {
        int tb2 = t0 + wm * 64 + m * 16 + r4;
        #pragma unroll
        for (int j = 0; j < 4; j++) {
            int t = tb2 + j;
            if (t < T) {
                float rvt = rvs[t - t0];
                float* orow = out + ((size_t)b * T + t) * NE + e0 + wn * 64 + (lane & 15);
                #pragma unroll
                for (int n = 0; n < 4; n++) orow[n * 16] = acc[m][n][j] * rvt;
            }
        }
    }

    // --- in-band out_w rows (needs rvs): overlaps C-write drain ---
    if (ib0 < ib1) {
        int tt = tid & 127, half = tid >> 7;
        if (tt < tcnt) {
            float ftl = fts[tt], rvl = rvs[tt];
            float* dstc = wout + (size_t)b * NL * T + t0 + tt;
            for (int l = ib0 + half; l < ib1; l += 2) {
                float z = (ftl - sm[l]) * si[l];
                dstc[(size_t)l * T] = __expf(fmaf(z, -0.5f * z, sa[l])) * rvl;
            }
        }
    }
}

extern "C" void kernel_launch(void* const* d_in, const int* in_sizes, int n_in,
                              void* d_out, int out_size, void* d_ws, size_t ws_size,
                              hipStream_t stream) {
    const float* x      = (const float*)d_in[0];
    const float* df     = (const float*)d_in[1];
    const int*   dint   = (const int*)d_in[2];
    const float* en     = (const float*)d_in[3];
    const float* pt     = (const float*)d_in[4];
    const int*   lens   = (const int*)d_in[5];
    const float* frames = (const float*)d_in[6];
    const float* wd     = (const float*)d_in[7];
    const float* bd     = (const float*)d_in[8];
    const float* wn     = (const float*)d_in[9];
    const float* bn     = (const float*)d_in[10];
    const float* wq     = (const float*)d_in[11];
    const float* bq     = (const float*)d_in[12];
    const float* wproj  = (const float*)d_in[13];
    const float* bproj  = (const float*)d_in[14];

    int T = in_sizes[6];
    int ntb = (T + 127) / 128;   // <= 32

    char* ws = (char*)d_ws;
    float* means   = (float*)(ws);             // B*L
    float* inv_std = (float*)(ws + 32768);     // B*L
    float* Aarr    = (float*)(ws + 65536);     // B*L
    float* dot8    = (float*)(ws + 98304);     // B*L*8 = 256 KB
    int2*  win     = (int2*)(ws + 360448);     // B*MAXTB
    u16*   XcT     = (u16*)(ws + 364544);      // B*E*L bf16 = 8.39 MB

    float* out_up = (float*)d_out;                 // (B,T,E)
    float* out_w  = out_up + (size_t)NB * T * NE;  // (B,L,T)

    k_xc<<<dim3(8, 8, NB), dim3(256), 0, stream>>>(x, en, pt, wn, bn, wq, bq, wproj,
                                                   XcT, dot8);
    k_pre<<<dim3(NB), dim3(512), 0, stream>>>(dint, df, lens, wproj, wd, bd, bproj,
                                              dot8, means, inv_std, Aarr, win, ntb);
    k_gemm<<<dim3(4, ntb, NB), dim3(256), 0, stream>>>(XcT, frames, means, inv_std,
                                                       Aarr, win, out_up, out_w, T);
}

// Round 14
// 54.284 us; speedup vs baseline: 1.5609x; 1.0053x over previous
//
#include <hip/hip_runtime.h>

typedef unsigned short u16;
typedef unsigned int u32;
typedef __attribute__((ext_vector_type(8))) short short8;
typedef __attribute__((ext_vector_type(4))) float f32x4;

#define LOG_SQRT_2PI 0.9189385332046727f
#define NB 16
#define NL 512
#define NE 512
#define ZWIN 20.0f
#define MAXTB 32

__device__ __forceinline__ u16 f2bf(float x) {
    u32 u = __builtin_bit_cast(u32, x);
    u += 0x7fffu + ((u >> 16) & 1u);
    return (u16)(u >> 16);
}

__device__ __forceinline__ void gload_lds16(const u16* g, u16* l) {
    __builtin_amdgcn_global_load_lds(
        (__attribute__((address_space(1))) void*)(u16*)g,
        (__attribute__((address_space(3))) void*)l,
        16, 0, 0);
}

// ---------------- K1: xc -> XcT[b][e][l] bf16 + per-eblock partial dot(xc, wproj) ----------------
__global__ void k_xc(const float* __restrict__ x, const float* __restrict__ en,
                     const float* __restrict__ pt,
                     const float* __restrict__ wn, const float* __restrict__ bn,
                     const float* __restrict__ wq, const float* __restrict__ bq,
                     const float* __restrict__ wproj,
                     u16* __restrict__ XcT, float* __restrict__ dot8) {
    __shared__ u16 tile[64][68];
    int b = blockIdx.z;
    int l0 = blockIdx.y * 64, e0 = blockIdx.x * 64;
    int tid = threadIdx.x;               // 256
    int c16 = tid & 15, rg = tid >> 4;   // 16 e-groups x 16 row-groups
    int e = e0 + c16 * 4;
    float wnA[12], wqA[12], bias[4], wp[4];
    {
        const float4* p = (const float4*)(wn + (size_t)e * 3);
        float4 a0 = p[0], a1 = p[1], a2 = p[2];
        wnA[0]=a0.x; wnA[1]=a0.y; wnA[2]=a0.z; wnA[3]=a0.w; wnA[4]=a1.x; wnA[5]=a1.y;
        wnA[6]=a1.z; wnA[7]=a1.w; wnA[8]=a2.x; wnA[9]=a2.y; wnA[10]=a2.z; wnA[11]=a2.w;
        const float4* q = (const float4*)(wq + (size_t)e * 3);
        float4 b0 = q[0], b1 = q[1], b2 = q[2];
        wqA[0]=b0.x; wqA[1]=b0.y; wqA[2]=b0.z; wqA[3]=b0.w; wqA[4]=b1.x; wqA[5]=b1.y;
        wqA[6]=b1.z; wqA[7]=b1.w; wqA[8]=b2.x; wqA[9]=b2.y; wqA[10]=b2.z; wqA[11]=b2.w;
        float4 bn4 = *(const float4*)(bn + e);
        float4 bq4 = *(const float4*)(bq + e);
        bias[0]=bn4.x+bq4.x; bias[1]=bn4.y+bq4.y; bias[2]=bn4.z+bq4.z; bias[3]=bn4.w+bq4.w;
        float4 wp4 = *(const float4*)(wproj + e);
        wp[0]=wp4.x; wp[1]=wp4.y; wp[2]=wp4.z; wp[3]=wp4.w;
    }
    int base = b * NL;
    #pragma unroll
    for (int it = 0; it < 4; ++it) {
        int ll = rg + 16 * it;
        int l = l0 + ll;
        float em1 = (l > 0)   ? en[base + l - 1] : 0.f;
        float ev  = en[base + l];
        float ep1 = (l < 511) ? en[base + l + 1] : 0.f;
        float pm1 = (l > 0)   ? pt[base + l - 1] : 0.f;
        float pv  = pt[base + l];
        float pp1 = (l < 511) ? pt[base + l + 1] : 0.f;
        float4 xv = *(const float4*)(x + ((size_t)(base + l)) * NE + e);
        float xa[4] = {xv.x, xv.y, xv.z, xv.w};
        float pd = 0.f;
        #pragma unroll
        for (int k = 0; k < 4; ++k) {
            float v = xa[k]
                    + wnA[k*3+0] * em1 + wnA[k*3+1] * ev + wnA[k*3+2] * ep1
                    + wqA[k*3+0] * pm1 + wqA[k*3+1] * pv + wqA[k*3+2] * pp1 + bias[k];
            tile[ll][c16 * 4 + k] = f2bf(v);
            pd = fmaf(v, wp[k], pd);
        }
        #pragma unroll
        for (int m = 8; m; m >>= 1) pd += __shfl_xor(pd, m);
        if (c16 == 0) dot8[((size_t)(base + l)) * 8 + blockIdx.x] = pd;
    }
    __syncthreads();
    int lr = tid >> 6, c = tid & 63;
    #pragma unroll 4
    for (int it = 0; it < 16; ++it) {
        int eo = lr + 4 * it;  // 0..63
        XcT[((size_t)b * NE + (e0 + eo)) * NL + l0 + c] = tile[c][eo];
    }
}

// ---------------- K2: taps(local) + wave-scan cumsum + ranges/inv_std/A + window table ----------------
__global__ void k_pre(const int* __restrict__ dint, const float* __restrict__ df,
                      const int* __restrict__ lens,
                      const float* __restrict__ wproj, const float* __restrict__ wd,
                      const float* __restrict__ bd, const float* __restrict__ bproj,
                      const float* __restrict__ dot8,
                      float* __restrict__ means, float* __restrict__ inv_std,
                      float* __restrict__ Aarr, int2* __restrict__ win, int ntb) {
    int b = blockIdx.x, l = threadIdx.x;  // 512 threads, 8 waves
    __shared__ float red[4][8];
    __shared__ float tarr[4];
    __shared__ float wsum[8], woff[8];
    __shared__ int slo[MAXTB], shi[MAXTB];
    int lane = l & 63, wv = l >> 6;
    {
        float wp = wproj[l];
        float v[4] = {wp * wd[l * 3 + 0], wp * wd[l * 3 + 1], wp * wd[l * 3 + 2], wp * bd[l]};
        #pragma unroll
        for (int i = 0; i < 4; i++) {
            float t = v[i];
            for (int m = 32; m; m >>= 1) t += __shfl_xor(t, m);
            if (lane == 0) red[i][wv] = t;
        }
    }
    if (l < ntb) { slo[l] = NL; shi[l] = -1; }
    // wave-level inclusive scan (durations are small ints -> f32-exact under any order)
    float d = (float)dint[b * NL + l];
    float run = d;
    #pragma unroll
    for (int off = 1; off < 64; off <<= 1) {
        float v = __shfl_up(run, off);
        if (lane >= off) run += v;
    }
    if (lane == 63) wsum[wv] = run;
    __syncthreads();
    if (l < 4) {
        float t = 0.f;
        for (int w2 = 0; w2 < 8; w2++) t += red[l][w2];
        if (l == 3) t += bproj[0];
        tarr[l] = t;
    }
    if (l < 8) {
        float acc = 0.f;
        for (int i = 0; i < l; i++) acc += wsum[i];  // exclusive over wave sums
        woff[l] = acc;
    }
    __syncthreads();
    float csum = run + woff[wv];
    float mean = csum - 0.5f * d;
    means[b * NL + l] = mean;
    int base = b * NL;
    float dot;
    {
        const float4* dp = (const float4*)(dot8 + ((size_t)(base + l)) * 8);
        float4 a = dp[0], bb4 = dp[1];
        dot = ((a.x + a.y) + (a.z + a.w)) + ((bb4.x + bb4.y) + (bb4.z + bb4.w));
    }
    float dm1 = (l > 0)   ? df[base + l - 1] : 0.f;
    float d0  = df[base + l];
    float dp1 = (l < 511) ? df[base + l + 1] : 0.f;
    float lin = dot + tarr[3]
              + tarr[0] * dm1 + tarr[1] * d0 + tarr[2] * dp1;
    float r = (lin > 20.f) ? lin : log1pf(expf(lin));
    bool pad = (l >= lens[b]);
    if (pad) r = 1.0f;
    float sd = fmaxf(r, 0.001f);
    inv_std[base + l] = 1.0f / sd;
    Aarr[base + l] = pad ? -1e30f : (-logf(sd) - LOG_SQRT_2PI);
    if (!pad) {
        float fl = mean - ZWIN * sd - 1.0f;
        float fh = mean + ZWIN * sd + 1.0f;
        for (int tb = 0; tb < ntb; ++tb) {
            float t_lo = tb * 128.0f + 0.5f, t_hi = tb * 128.0f + 127.5f;
            if (fl <= t_hi && fh >= t_lo) {
                atomicMin(&slo[tb], l);
                atomicMax(&shi[tb], l);
            }
        }
    }
    __syncthreads();
    if (l < ntb) win[b * MAXTB + l] = make_int2(slo[l], shi[l]);
}

// ---------------- K3: banded GEMM on UNNORMALIZED P; rn folded into C-write ----------------
__global__ __launch_bounds__(256) void k_gemm(const u16* __restrict__ XcT,
                                              const float* __restrict__ frames,
                                              const float* __restrict__ means,
                                              const float* __restrict__ inv_std,
                                              const float* __restrict__ Aarr,
                                              const int2* __restrict__ win,
                                              float* __restrict__ out,
                                              float* __restrict__ wout, int T) {
    __shared__ float sm[NL], si[NL], sa[NL];
    __shared__ float fts[128];
    __shared__ float part[2][128];
    __shared__ float rvs[128];
    __shared__ u16 At[2][128][32];
    __shared__ u16 Bt[2][128][32];
    int b = blockIdx.z;
    int t0 = blockIdx.y * 128;
    int e0 = blockIdx.x * 128;
    int tid = threadIdx.x;
    int lane = tid & 63, wid = tid >> 6;
    int wm = wid >> 1, wn = wid & 1;
    const u16* Bb = XcT + (size_t)b * NE * NL;

    // independent loads first: frames + window (in flight during zero-fill issue)
    float ftv = (tid < 128 && t0 + tid < T) ? frames[t0 + tid] : -1e9f;
    int2 w = win[b * MAXTB + blockIdx.y];
    int ks0 = 0, nst = 0;
    if (w.x <= w.y) { ks0 = w.x >> 5; nst = (w.y >> 5) - ks0 + 1; }
    int bl0 = ks0 * 32, bl1 = (ks0 + nst) * 32;
    if (tid < 128) fts[tid] = ftv;

    // --- out_w zero-fill (depends only on win) ---
    int tcnt = T - t0; if (tcnt > 128) tcnt = 128;
    int rbeg = e0, rend = e0 + 128;
    int ib0 = bl0 > rbeg ? bl0 : rbeg;
    int ib1 = bl1 < rend ? bl1 : rend;
    {
        int t4 = (tid & 31) * 4, rsub = tid >> 5;  // 8 rows per pass, float4 across t
        bool t4full = (t4 + 4 <= tcnt);
        float4 z4 = make_float4(0.f, 0.f, 0.f, 0.f);
        auto zfill = [&](int r0, int r1) {
            for (int l = r0 + rsub; l < r1; l += 8) {
                float* d = wout + ((size_t)b * NL + l) * T + t0 + t4;
                if (t4full) *(float4*)d = z4;
                else { for (int u = 0; u < 4 && t4 + u < tcnt; ++u) d[u] = 0.f; }
            }
        };
        if (ib0 >= ib1) zfill(rbeg, rend);
        else { zfill(rbeg, ib0); zfill(ib1, rend); }
    }

    // band-restricted stats load
    for (int i = bl0 + tid; i < bl1; i += 256) {
        sm[i] = means[b * NL + i];
        si[i] = inv_std[b * NL + i];
        sa[i] = Aarr[b * NL + i];
    }

    __syncthreads();  // sm/si/sa, fts ready

    int ta = tid >> 1;        // A-row (t offset) this thread fills
    int ha = (tid & 1) * 16;  // which 16-col half
    float ft = fts[ta];
    float bsum = 0.f;         // this thread's share of row ta's band sum

    int srow = wid * 32 + (lane >> 2);
    int skc = (lane & 3) * 8;

    f32x4 acc[4][4];
    #pragma unroll
    for (int m = 0; m < 4; m++)
        #pragma unroll
        for (int n = 0; n < 4; n++)
            #pragma unroll
            for (int k = 0; k < 4; k++) acc[m][n][k] = 0.0f;

    auto stage = [&](int buf, int ks) {
        int l0 = ks * 32;
        const u16* gb = Bb + (size_t)(e0 + srow) * NL + l0 + skc;
        gload_lds16(gb, &Bt[buf][wid * 32][0]);
        gload_lds16(gb + 16 * NL, &Bt[buf][wid * 32 + 16][0]);
        u32 pk[8];
        #pragma unroll
        for (int jj = 0; jj < 8; ++jj) {
            int l0j = l0 + ha + jj * 2;
            float z0 = (ft - sm[l0j]) * si[l0j];
            float p0 = __expf(fmaf(z0, -0.5f * z0, sa[l0j]));
            float z1 = (ft - sm[l0j + 1]) * si[l0j + 1];
            float p1 = __expf(fmaf(z1, -0.5f * z1, sa[l0j + 1]));
            bsum += p0 + p1;
            pk[jj] = (u32)f2bf(p0) | ((u32)f2bf(p1) << 16);
        }
        *(uint4*)&At[buf][ta][ha]     = make_uint4(pk[0], pk[1], pk[2], pk[3]);
        *(uint4*)&At[buf][ta][ha + 8] = make_uint4(pk[4], pk[5], pk[6], pk[7]);
    };

    int fr = lane & 15, fk = (lane >> 4) * 8;
    if (nst > 0) {
        stage(0, ks0);
        for (int s = 0; s < nst; ++s) {
            __syncthreads();  // buf[s&1] (ds_writes + gload_lds) visible
            if (s + 1 < nst) stage((s + 1) & 1, ks0 + s + 1);
            int buf = s & 1;
            short8 a[4], bb[4];
            #pragma unroll
            for (int m = 0; m < 4; m++)
                a[m] = *(const short8*)&At[buf][wm * 64 + m * 16 + fr][fk];
            #pragma unroll
            for (int n = 0; n < 4; n++)
                bb[n] = *(const short8*)&Bt[buf][wn * 64 + n * 16 + fr][fk];
            #pragma unroll
            for (int m = 0; m < 4; m++)
                #pragma unroll
                for (int n = 0; n < 4; n++)
                    acc[m][n] = __builtin_amdgcn_mfma_f32_16x16x32_bf16(a[m], bb[n], acc[m][n], 0, 0, 0);
        }
    }

    // --- combine band sums -> rvs (free: exps were computed for At anyway) ---
    part[tid & 1][ta] = bsum;
    __syncthreads();
    if (tid < 128) rvs[tid] = 1.0f / (part[0][tid] + part[1][tid] + 1e-20f);
    __syncthreads();

    // --- C-write, scaled by rn[t] ---
    int r4 = (lane >> 4) * 4;
    #pragma unroll
    for (int m = 0; m < 4; m++) {
        int tb2 = t0 + wm * 64 + m * 16 + r4;
        #pragma unroll
        for (int j = 0; j < 4; j++) {
            int t = tb2 + j;
            if (t < T) {
                float rvt = rvs[t - t0];
                float* orow = out + ((size_t)b * T + t) * NE + e0 + wn * 64 + (lane & 15);
                #pragma unroll
                for (int n = 0; n < 4; n++) orow[n * 16] = acc[m][n][j] * rvt;
            }
        }
    }

    // --- in-band out_w rows (needs rvs): overlaps C-write drain ---
    if (ib0 < ib1) {
        int tt = tid & 127, half = tid >> 7;
        if (tt < tcnt) {
            float ftl = fts[tt], rvl = rvs[tt];
            float* dstc = wout + (size_t)b * NL * T + t0 + tt;
            for (int l = ib0 + half; l < ib1; l += 2) {
                float z = (ftl - sm[l]) * si[l];
                dstc[(size_t)l * T] = __expf(fmaf(z, -0.5f * z, sa[l])) * rvl;
            }
        }
    }
}

extern "C" void kernel_launch(void* const* d_in, const int* in_sizes, int n_in,
                              void* d_out, int out_size, void* d_ws, size_t ws_size,
                              hipStream_t stream) {
    const float* x      = (const float*)d_in[0];
    const float* df     = (const float*)d_in[1];
    const int*   dint   = (const int*)d_in[2];
    const float* en     = (const float*)d_in[3];
    const float* pt     = (const float*)d_in[4];
    const int*   lens   = (const int*)d_in[5];
    const float* frames = (const float*)d_in[6];
    const float* wd     = (const float*)d_in[7];
    const float* bd     = (const float*)d_in[8];
    const float* wn     = (const float*)d_in[9];
    const float* bn     = (const float*)d_in[10];
    const float* wq     = (const float*)d_in[11];
    const float* bq     = (const float*)d_in[12];
    const float* wproj  = (const float*)d_in[13];
    const float* bproj  = (const float*)d_in[14];

    int T = in_sizes[6];
    int ntb = (T + 127) / 128;   // <= 32

    char* ws = (char*)d_ws;
    float* means   = (float*)(ws);             // B*L
    float* inv_std = (float*)(ws + 32768);     // B*L
    float* Aarr    = (float*)(ws + 65536);     // B*L
    float* dot8    = (float*)(ws + 98304);     // B*L*8 = 256 KB
    int2*  win     = (int2*)(ws + 360448);     // B*MAXTB
    u16*   XcT     = (u16*)(ws + 364544);      // B*E*L bf16 = 8.39 MB

    float* out_up = (float*)d_out;                 // (B,T,E)
    float* out_w  = out_up + (size_t)NB * T * NE;  // (B,L,T)

    k_xc<<<dim3(8, 8, NB), dim3(256), 0, stream>>>(x, en, pt, wn, bn, wq, bq, wproj,
                                                   XcT, dot8);
    k_pre<<<dim3(NB), dim3(512), 0, stream>>>(dint, df, lens, wproj, wd, bd, bproj,
                                              dot8, means, inv_std, Aarr, win, ntb);
    k_gemm<<<dim3(4, ntb, NB), dim3(256), 0, stream>>>(XcT, frames, means, inv_std,
                                                       Aarr, win, out_up, out_w, T);
}